// Round 3
// baseline (627.347 us; speedup 1.0000x reference)
//
#include <hip/hip_runtime.h>
#include <cstdint>
#include <cstddef>

typedef unsigned short u16;
typedef __attribute__((ext_vector_type(8))) short s16x8;      // 8 bf16 = 4 VGPRs (MFMA A/B frag)
typedef __attribute__((ext_vector_type(8))) unsigned short u16x8;
typedef __attribute__((ext_vector_type(4))) float f32x4;      // MFMA C/D frag / float4 load

#define D_MODEL 1024
#define DH 64
#define BS 256
// B*S = 16384 tokens, 64 blocks of 256, 16 heads. All external tensors are FLOAT32.

__device__ __forceinline__ u16 f2bf(float f) {
  union { float f; unsigned int i; } x; x.f = f;
  unsigned int r = x.i + 0x7fffu + ((x.i >> 16) & 1u);   // RNE
  return (u16)(r >> 16);
}

// ---------------- W transpose+cast: Wt[n][k] = bf16(W[k][n]) (1024x1024 f32 -> bf16, x4) ----------------
__global__ __launch_bounds__(256) void transpose_w(const float* __restrict__ w0,
                                                   const float* __restrict__ w1,
                                                   const float* __restrict__ w2,
                                                   const float* __restrict__ w3,
                                                   u16* __restrict__ out) {
  __shared__ u16 tile[64][65];
  const int z = blockIdx.z;
  const float* W = (z == 0) ? w0 : (z == 1) ? w1 : (z == 2) ? w2 : w3;
  u16* O = out + (size_t)z * (D_MODEL * D_MODEL);
  const int kb = blockIdx.y * 64, nb = blockIdx.x * 64;
  const int t = threadIdx.x;
#pragma unroll
  for (int i = 0; i < 16; ++i) {
    int e = i * 256 + t;
    int r = e >> 6, c = e & 63;
    tile[r][c] = f2bf(W[(size_t)(kb + r) * D_MODEL + nb + c]);
  }
  __syncthreads();
#pragma unroll
  for (int i = 0; i < 16; ++i) {
    int e = i * 256 + t;
    int r = e >> 6, c = e & 63;
    O[(size_t)(nb + r) * D_MODEL + kb + c] = tile[c][r];
  }
}

// ---------------- QKV GEMM: Out_z[m][n] = bf16( x[m][:] @ W_z[:][n] + b_z[n] ) ----------------
// x is f32 (converted to bf16 in staging); Wt is bf16 [n][k]; outputs bf16.
// 128x128 tile, BK=64, 256 threads (4 waves, 64x64 quadrant each, 4x4 16x16x32 MFMA)
__global__ __launch_bounds__(256) void gemm_qkv(
    const float* __restrict__ A, const u16* __restrict__ WtBase,
    const float* __restrict__ bias0, const float* __restrict__ bias1, const float* __restrict__ bias2,
    u16* __restrict__ out0, u16* __restrict__ out1, u16* __restrict__ out2) {
  __shared__ u16 As[128 * 64];
  __shared__ u16 Bs[128 * 64];
  const int z = blockIdx.z;
  const u16* Wt = WtBase + (size_t)z * (D_MODEL * D_MODEL);
  const float* bias = (z == 0) ? bias0 : ((z == 1) ? bias1 : bias2);
  u16* Out = (z == 0) ? out0 : ((z == 1) ? out1 : out2);
  const int rowBase = blockIdx.y * 128;
  const int colBase = blockIdx.x * 128;
  const int t = threadIdx.x;
  const int wave = t >> 6, lane = t & 63, l15 = lane & 15, q4 = lane >> 4;
  const int wr = (wave >> 1) * 64, wc = (wave & 1) * 64;

  f32x4 acc[4][4];
#pragma unroll
  for (int i = 0; i < 4; ++i)
#pragma unroll
    for (int j = 0; j < 4; ++j) acc[i][j] = {0.f, 0.f, 0.f, 0.f};

  for (int k0 = 0; k0 < D_MODEL; k0 += 64) {
#pragma unroll
    for (int i = 0; i < 4; ++i) {
      int e = i * 256 + t;
      const float* src = A + (size_t)(rowBase + (e >> 3)) * D_MODEL + k0 + (e & 7) * 8;
      f32x4 a0 = *(const f32x4*)src;
      f32x4 a1 = *(const f32x4*)(src + 4);
      u16x8 v;
#pragma unroll
      for (int j = 0; j < 4; ++j) { v[j] = f2bf(a0[j]); v[j + 4] = f2bf(a1[j]); }
      *(u16x8*)(As + e * 8) = v;
    }
#pragma unroll
    for (int i = 0; i < 4; ++i) {
      int e = i * 256 + t;
      u16x8 v = *(const u16x8*)(Wt + (size_t)(colBase + (e >> 3)) * D_MODEL + k0 + (e & 7) * 8);
      *(u16x8*)(Bs + e * 8) = v;
    }
    __syncthreads();
#pragma unroll
    for (int kk = 0; kk < 2; ++kk) {
      s16x8 af[4], bf[4];
#pragma unroll
      for (int mt = 0; mt < 4; ++mt)
        af[mt] = *(const s16x8*)(As + (wr + mt * 16 + l15) * 64 + kk * 32 + q4 * 8);
#pragma unroll
      for (int nt = 0; nt < 4; ++nt)
        bf[nt] = *(const s16x8*)(Bs + (wc + nt * 16 + l15) * 64 + kk * 32 + q4 * 8);
#pragma unroll
      for (int mt = 0; mt < 4; ++mt)
#pragma unroll
        for (int nt = 0; nt < 4; ++nt)
          acc[mt][nt] = __builtin_amdgcn_mfma_f32_16x16x32_bf16(af[mt], bf[nt], acc[mt][nt], 0, 0, 0);
    }
    __syncthreads();
  }

#pragma unroll
  for (int nt = 0; nt < 4; ++nt) {
    int col = colBase + wc + nt * 16 + l15;
    float bv = bias[col];
#pragma unroll
    for (int mt = 0; mt < 4; ++mt) {
      int row0 = rowBase + wr + mt * 16 + q4 * 4;
#pragma unroll
      for (int r = 0; r < 4; ++r)
        Out[(size_t)(row0 + r) * D_MODEL + col] = f2bf(acc[mt][nt][r] + bv);
    }
  }
}

// ---------------- O-proj GEMM: out[m][n] = f32( Ow[m][:] @ Wo[:][n] + bo[n] ) ----------------
// Ow bf16, Wt bf16 [n][k], output FLOAT32 to d_out.
__global__ __launch_bounds__(256) void gemm_oproj(
    const u16* __restrict__ A, const u16* __restrict__ Wt,
    const float* __restrict__ bias, float* __restrict__ Out) {
  __shared__ u16 As[128 * 64];
  __shared__ u16 Bs[128 * 64];
  const int rowBase = blockIdx.y * 128;
  const int colBase = blockIdx.x * 128;
  const int t = threadIdx.x;
  const int wave = t >> 6, lane = t & 63, l15 = lane & 15, q4 = lane >> 4;
  const int wr = (wave >> 1) * 64, wc = (wave & 1) * 64;

  f32x4 acc[4][4];
#pragma unroll
  for (int i = 0; i < 4; ++i)
#pragma unroll
    for (int j = 0; j < 4; ++j) acc[i][j] = {0.f, 0.f, 0.f, 0.f};

  for (int k0 = 0; k0 < D_MODEL; k0 += 64) {
#pragma unroll
    for (int i = 0; i < 4; ++i) {
      int e = i * 256 + t;
      u16x8 v = *(const u16x8*)(A + (size_t)(rowBase + (e >> 3)) * D_MODEL + k0 + (e & 7) * 8);
      *(u16x8*)(As + e * 8) = v;
    }
#pragma unroll
    for (int i = 0; i < 4; ++i) {
      int e = i * 256 + t;
      u16x8 v = *(const u16x8*)(Wt + (size_t)(colBase + (e >> 3)) * D_MODEL + k0 + (e & 7) * 8);
      *(u16x8*)(Bs + e * 8) = v;
    }
    __syncthreads();
#pragma unroll
    for (int kk = 0; kk < 2; ++kk) {
      s16x8 af[4], bf[4];
#pragma unroll
      for (int mt = 0; mt < 4; ++mt)
        af[mt] = *(const s16x8*)(As + (wr + mt * 16 + l15) * 64 + kk * 32 + q4 * 8);
#pragma unroll
      for (int nt = 0; nt < 4; ++nt)
        bf[nt] = *(const s16x8*)(Bs + (wc + nt * 16 + l15) * 64 + kk * 32 + q4 * 8);
#pragma unroll
      for (int mt = 0; mt < 4; ++mt)
#pragma unroll
        for (int nt = 0; nt < 4; ++nt)
          acc[mt][nt] = __builtin_amdgcn_mfma_f32_16x16x32_bf16(af[mt], bf[nt], acc[mt][nt], 0, 0, 0);
    }
    __syncthreads();
  }

#pragma unroll
  for (int nt = 0; nt < 4; ++nt) {
    int col = colBase + wc + nt * 16 + l15;
    float bv = bias[col];
#pragma unroll
    for (int mt = 0; mt < 4; ++mt) {
      int row0 = rowBase + wr + mt * 16 + q4 * 4;
#pragma unroll
      for (int r = 0; r < 4; ++r)
        Out[(size_t)(row0 + r) * D_MODEL + col] = acc[mt][nt][r] + bv;
    }
  }
}

// ---------------- Attention: one WG (128 thr = 2 waves) per (block n, head h) ----------------
// Q,K,V,O: bf16 [token][1024]; this WG uses rows n*256..+255, cols h*64..+63.
// O aliases Q (per-WG slice read strictly before write; slices disjoint across WGs).
__global__ __launch_bounds__(128) void attn(const u16* __restrict__ Q, const u16* __restrict__ K,
                                            const u16* __restrict__ V, u16* __restrict__ O) {
  __shared__ u16 vt[64 * 264];        // V^T: [d][tok], row stride 264
  __shared__ u16 pl[2 * 16 * 264];    // per-wave P: [wave][16 rows][256(+pad) cols]
  const int g = blockIdx.x;
  const int n = g >> 4, h = g & 15;
  const size_t base = (size_t)n * BS * D_MODEL + (size_t)h * DH;
  const u16* Qb = Q + base;
  const u16* Kb = K + base;
  const u16* Vb = V + base;
  u16* Ob = O + base;
  const int t = threadIdx.x, wave = t >> 6, lane = t & 63, l15 = lane & 15, q4 = lane >> 4;

#pragma unroll
  for (int i = 0; i < 16; ++i) {
    int p = i * 128 + t;
    int d = p & 63, tok8 = p >> 6;
    u16x8 v;
#pragma unroll
    for (int j = 0; j < 8; ++j) v[j] = Vb[(size_t)(tok8 * 8 + j) * D_MODEL + d];
    *(u16x8*)(vt + d * 264 + tok8 * 8) = v;
  }
  __syncthreads();

  u16* pw = pl + wave * 16 * 264;

  for (int pass = 0; pass < 8; ++pass) {
    const int r0 = pass * 32 + wave * 16;
    const int a = r0 >> 4;

    s16x8 aq[2];
#pragma unroll
    for (int kk = 0; kk < 2; ++kk)
      aq[kk] = *(const s16x8*)(Qb + (size_t)(r0 + l15) * D_MODEL + kk * 32 + q4 * 8);

    f32x4 sc[16];
#pragma unroll
    for (int i = 0; i < 16; ++i) sc[i] = {0.f, 0.f, 0.f, 0.f};

#pragma unroll
    for (int nt = 0; nt < 16; ++nt) {
      if (nt > a) break;
#pragma unroll
      for (int kk = 0; kk < 2; ++kk) {
        s16x8 bk = *(const s16x8*)(Kb + (size_t)(nt * 16 + l15) * D_MODEL + kk * 32 + q4 * 8);
        sc[nt] = __builtin_amdgcn_mfma_f32_16x16x32_bf16(aq[kk], bk, sc[nt], 0, 0, 0);
      }
    }

    float mrow[4] = {-3e38f, -3e38f, -3e38f, -3e38f};
#pragma unroll
    for (int nt = 0; nt < 16; ++nt) {
      if (nt > a) break;
#pragma unroll
      for (int r = 0; r < 4; ++r) {
        int col = nt * 16 + l15;
        int row = r0 + q4 * 4 + r;
        float s = (col > row) ? -1.0e9f : sc[nt][r] * 0.125f;
        sc[nt][r] = s;
        mrow[r] = fmaxf(mrow[r], s);
      }
    }
#pragma unroll
    for (int r = 0; r < 4; ++r)
#pragma unroll
      for (int off = 1; off < 16; off <<= 1)
        mrow[r] = fmaxf(mrow[r], __shfl_xor(mrow[r], off, 64));

    float lrow[4] = {0.f, 0.f, 0.f, 0.f};
#pragma unroll
    for (int nt = 0; nt < 16; ++nt) {
      if (nt > a) break;
#pragma unroll
      for (int r = 0; r < 4; ++r) {
        float e = exp2f((sc[nt][r] - mrow[r]) * 1.44269504f);
        sc[nt][r] = e;
        lrow[r] += e;
      }
    }
#pragma unroll
    for (int r = 0; r < 4; ++r)
#pragma unroll
      for (int off = 1; off < 16; off <<= 1)
        lrow[r] += __shfl_xor(lrow[r], off, 64);

#pragma unroll
    for (int nt = 0; nt < 16; ++nt) {
      if (nt > a) break;
#pragma unroll
      for (int r = 0; r < 4; ++r)
        pw[(q4 * 4 + r) * 264 + nt * 16 + l15] = f2bf(sc[nt][r]);
    }
    if ((a & 1) == 0) {
#pragma unroll
      for (int r = 0; r < 4; ++r)
        pw[(q4 * 4 + r) * 264 + (a + 1) * 16 + l15] = 0;
    }
    const int ktmax = (a + 2) >> 1;

    f32x4 oc[4];
#pragma unroll
    for (int i = 0; i < 4; ++i) oc[i] = {0.f, 0.f, 0.f, 0.f};
#pragma unroll
    for (int kt = 0; kt < 8; ++kt) {
      if (kt >= ktmax) break;
      s16x8 ap = *(const s16x8*)(pw + l15 * 264 + kt * 32 + q4 * 8);
#pragma unroll
      for (int dt = 0; dt < 4; ++dt) {
        s16x8 bv = *(const s16x8*)(vt + (dt * 16 + l15) * 264 + kt * 32 + q4 * 8);
        oc[dt] = __builtin_amdgcn_mfma_f32_16x16x32_bf16(ap, bv, oc[dt], 0, 0, 0);
      }
    }

    float inv[4];
#pragma unroll
    for (int r = 0; r < 4; ++r) inv[r] = 1.0f / lrow[r];
#pragma unroll
    for (int dt = 0; dt < 4; ++dt)
#pragma unroll
      for (int r = 0; r < 4; ++r)
        Ob[(size_t)(r0 + q4 * 4 + r) * D_MODEL + dt * 16 + l15] = f2bf(oc[dt][r] * inv[r]);
  }
}

extern "C" void kernel_launch(void* const* d_in, const int* in_sizes, int n_in,
                              void* d_out, int out_size, void* d_ws, size_t ws_size,
                              hipStream_t stream) {
  const float* x  = (const float*)d_in[0];
  const float* Wq = (const float*)d_in[1];
  const float* bq = (const float*)d_in[2];
  const float* Wk = (const float*)d_in[3];
  const float* bk = (const float*)d_in[4];
  const float* Wv = (const float*)d_in[5];
  const float* bv = (const float*)d_in[6];
  const float* Wo = (const float*)d_in[7];
  const float* bo = (const float*)d_in[8];
  float* out = (float*)d_out;

  // ws (bf16 internal): Wt 4x1M, Q/K/V 16M each. O aliases Q. Total 104 MB.
  u16* ws = (u16*)d_ws;
  u16* Wt = ws;
  u16* Qw = ws + (size_t)4 * 1048576;
  u16* Kw = Qw + (size_t)16777216;
  u16* Vw = Kw + (size_t)16777216;
  u16* Ow = Qw;   // alias

  transpose_w<<<dim3(16, 16, 4), 256, 0, stream>>>(Wq, Wk, Wv, Wo, Wt);
  gemm_qkv<<<dim3(8, 128, 3), 256, 0, stream>>>(x, Wt, bq, bk, bv, Qw, Kw, Vw);
  attn<<<dim3(64 * 16), 128, 0, stream>>>(Qw, Kw, Vw, Ow);
  gemm_oproj<<<dim3(8, 128, 1), 256, 0, stream>>>(Ow, Wt + (size_t)3 * 1048576, bo, out);
}

// Round 4
// 568.732 us; speedup vs baseline: 1.1031x; 1.1031x over previous
//
#include <hip/hip_runtime.h>
#include <cstdint>
#include <cstddef>

typedef unsigned short u16;
typedef __attribute__((ext_vector_type(8))) short s16x8;      // 8 bf16 = 4 VGPRs (MFMA A/B frag)
typedef __attribute__((ext_vector_type(8))) unsigned short u16x8;
typedef __attribute__((ext_vector_type(4))) float f32x4;      // MFMA C/D frag / float4 load

#define D_MODEL 1024
#define DH 64
#define BS 256
// B*S = 16384 tokens, 64 blocks of 256, 16 heads. External tensors are FLOAT32; internal bf16.

__device__ __forceinline__ u16 f2bf(float f) {
  union { float f; unsigned int i; } x; x.f = f;
  unsigned int r = x.i + 0x7fffu + ((x.i >> 16) & 1u);   // RNE
  return (u16)(r >> 16);
}

__device__ __forceinline__ void gl_lds16(const u16* g, u16* l) {
  __builtin_amdgcn_global_load_lds((const __attribute__((address_space(1))) void*)g,
                                   (__attribute__((address_space(3))) void*)l, 16, 0, 0);
}

// ---------------- cast x: f32 -> bf16, 16.7M elems ----------------
__global__ __launch_bounds__(256) void cast_x(const float* __restrict__ x, u16* __restrict__ xb) {
  int i = (blockIdx.x * 256 + threadIdx.x) * 8;
  f32x4 a0 = *(const f32x4*)(x + i);
  f32x4 a1 = *(const f32x4*)(x + i + 4);
  u16x8 v;
#pragma unroll
  for (int j = 0; j < 4; ++j) { v[j] = f2bf(a0[j]); v[j + 4] = f2bf(a1[j]); }
  *(u16x8*)(xb + i) = v;
}

// ---------------- W transpose+cast: Wt[n][k] = bf16(W[k][n]) (1024x1024 f32 -> bf16, x4) ----------------
__global__ __launch_bounds__(256) void transpose_w(const float* __restrict__ w0,
                                                   const float* __restrict__ w1,
                                                   const float* __restrict__ w2,
                                                   const float* __restrict__ w3,
                                                   u16* __restrict__ out) {
  __shared__ u16 tile[64][65];
  const int z = blockIdx.z;
  const float* W = (z == 0) ? w0 : (z == 1) ? w1 : (z == 2) ? w2 : w3;
  u16* O = out + (size_t)z * (D_MODEL * D_MODEL);
  const int kb = blockIdx.y * 64, nb = blockIdx.x * 64;
  const int t = threadIdx.x;
#pragma unroll
  for (int i = 0; i < 16; ++i) {
    int e = i * 256 + t;
    int r = e >> 6, c = e & 63;
    tile[r][c] = f2bf(W[(size_t)(kb + r) * D_MODEL + nb + c]);
  }
  __syncthreads();
#pragma unroll
  for (int i = 0; i < 16; ++i) {
    int e = i * 256 + t;
    int r = e >> 6, c = e & 63;
    O[(size_t)(nb + r) * D_MODEL + kb + c] = tile[c][r];
  }
}

// ---------------- QKV GEMM (m97 structure): Out_z = bf16( xb @ W_z + b_z ) ----------------
// A bf16 [m][k], Wt bf16 [n][k]; global_load_lds width-16 staging; 128x128 tile, BK=64.
__global__ __launch_bounds__(256) void gemm_qkv(
    const u16* __restrict__ A, const u16* __restrict__ WtBase,
    const float* __restrict__ bias0, const float* __restrict__ bias1, const float* __restrict__ bias2,
    u16* __restrict__ out0, u16* __restrict__ out1, u16* __restrict__ out2) {
  __shared__ u16 As[128 * 64];
  __shared__ u16 Bs[128 * 64];
  const int z = blockIdx.z;
  const u16* Wt = WtBase + (size_t)z * (D_MODEL * D_MODEL);
  const float* bias = (z == 0) ? bias0 : ((z == 1) ? bias1 : bias2);
  u16* Out = (z == 0) ? out0 : ((z == 1) ? out1 : out2);
  const int rowBase = blockIdx.y * 128;
  const int colBase = blockIdx.x * 128;
  const int t = threadIdx.x;
  const int wave = t >> 6, lane = t & 63, l15 = lane & 15, q4 = lane >> 4;
  const int wr = (wave >> 1) * 64, wc = (wave & 1) * 64;

  f32x4 acc[4][4];
#pragma unroll
  for (int i = 0; i < 4; ++i)
#pragma unroll
    for (int j = 0; j < 4; ++j) acc[i][j] = {0.f, 0.f, 0.f, 0.f};

  for (int k0 = 0; k0 < D_MODEL; k0 += 64) {
#pragma unroll
    for (int i = 0; i < 4; ++i) {
      int e = i * 256 + t;
      gl_lds16(A + (size_t)(rowBase + (e >> 3)) * D_MODEL + k0 + (e & 7) * 8, As + e * 8);
    }
#pragma unroll
    for (int i = 0; i < 4; ++i) {
      int e = i * 256 + t;
      gl_lds16(Wt + (size_t)(colBase + (e >> 3)) * D_MODEL + k0 + (e & 7) * 8, Bs + e * 8);
    }
    __syncthreads();
#pragma unroll
    for (int kk = 0; kk < 2; ++kk) {
      s16x8 af[4], bf[4];
#pragma unroll
      for (int mt = 0; mt < 4; ++mt)
        af[mt] = *(const s16x8*)(As + (wr + mt * 16 + l15) * 64 + kk * 32 + q4 * 8);
#pragma unroll
      for (int nt = 0; nt < 4; ++nt)
        bf[nt] = *(const s16x8*)(Bs + (wc + nt * 16 + l15) * 64 + kk * 32 + q4 * 8);
#pragma unroll
      for (int mt = 0; mt < 4; ++mt)
#pragma unroll
        for (int nt = 0; nt < 4; ++nt)
          acc[mt][nt] = __builtin_amdgcn_mfma_f32_16x16x32_bf16(af[mt], bf[nt], acc[mt][nt], 0, 0, 0);
    }
    __syncthreads();
  }

#pragma unroll
  for (int nt = 0; nt < 4; ++nt) {
    int col = colBase + wc + nt * 16 + l15;
    float bv = bias[col];
#pragma unroll
    for (int mt = 0; mt < 4; ++mt) {
      int row0 = rowBase + wr + mt * 16 + q4 * 4;
#pragma unroll
      for (int r = 0; r < 4; ++r)
        Out[(size_t)(row0 + r) * D_MODEL + col] = f2bf(acc[mt][nt][r] + bv);
    }
  }
}

// ---------------- O-proj GEMM (m97 structure): out = f32( Ow @ Wo + bo ) ----------------
__global__ __launch_bounds__(256) void gemm_oproj(
    const u16* __restrict__ A, const u16* __restrict__ Wt,
    const float* __restrict__ bias, float* __restrict__ Out) {
  __shared__ u16 As[128 * 64];
  __shared__ u16 Bs[128 * 64];
  const int rowBase = blockIdx.y * 128;
  const int colBase = blockIdx.x * 128;
  const int t = threadIdx.x;
  const int wave = t >> 6, lane = t & 63, l15 = lane & 15, q4 = lane >> 4;
  const int wr = (wave >> 1) * 64, wc = (wave & 1) * 64;

  f32x4 acc[4][4];
#pragma unroll
  for (int i = 0; i < 4; ++i)
#pragma unroll
    for (int j = 0; j < 4; ++j) acc[i][j] = {0.f, 0.f, 0.f, 0.f};

  for (int k0 = 0; k0 < D_MODEL; k0 += 64) {
#pragma unroll
    for (int i = 0; i < 4; ++i) {
      int e = i * 256 + t;
      gl_lds16(A + (size_t)(rowBase + (e >> 3)) * D_MODEL + k0 + (e & 7) * 8, As + e * 8);
    }
#pragma unroll
    for (int i = 0; i < 4; ++i) {
      int e = i * 256 + t;
      gl_lds16(Wt + (size_t)(colBase + (e >> 3)) * D_MODEL + k0 + (e & 7) * 8, Bs + e * 8);
    }
    __syncthreads();
#pragma unroll
    for (int kk = 0; kk < 2; ++kk) {
      s16x8 af[4], bf[4];
#pragma unroll
      for (int mt = 0; mt < 4; ++mt)
        af[mt] = *(const s16x8*)(As + (wr + mt * 16 + l15) * 64 + kk * 32 + q4 * 8);
#pragma unroll
      for (int nt = 0; nt < 4; ++nt)
        bf[nt] = *(const s16x8*)(Bs + (wc + nt * 16 + l15) * 64 + kk * 32 + q4 * 8);
#pragma unroll
      for (int mt = 0; mt < 4; ++mt)
#pragma unroll
        for (int nt = 0; nt < 4; ++nt)
          acc[mt][nt] = __builtin_amdgcn_mfma_f32_16x16x32_bf16(af[mt], bf[nt], acc[mt][nt], 0, 0, 0);
    }
    __syncthreads();
  }

#pragma unroll
  for (int nt = 0; nt < 4; ++nt) {
    int col = colBase + wc + nt * 16 + l15;
    float bv = bias[col];
#pragma unroll
    for (int mt = 0; mt < 4; ++mt) {
      int row0 = rowBase + wr + mt * 16 + q4 * 4;
#pragma unroll
      for (int r = 0; r < 4; ++r)
        Out[(size_t)(row0 + r) * D_MODEL + col] = acc[mt][nt][r] + bv;
    }
  }
}

// ---------------- Attention: one WG (128 thr = 2 waves) per (block n, head h) ----------------
// Q,K,V,O: bf16 [token][1024]; this WG uses rows n*256..+255, cols h*64..+63.
// O aliases Q (per-WG slice read strictly before write; slices disjoint across WGs).
__global__ __launch_bounds__(128) void attn(const u16* __restrict__ Q, const u16* __restrict__ K,
                                            const u16* __restrict__ V, u16* __restrict__ O) {
  __shared__ u16 vt[64 * 264];        // V^T: [d][tok], row stride 264
  __shared__ u16 pl[2 * 16 * 264];    // per-wave P: [wave][16 rows][256(+pad) cols]
  const int g = blockIdx.x;
  const int n = g >> 4, h = g & 15;
  const size_t base = (size_t)n * BS * D_MODEL + (size_t)h * DH;
  const u16* Qb = Q + base;
  const u16* Kb = K + base;
  const u16* Vb = V + base;
  u16* Ob = O + base;
  const int t = threadIdx.x, wave = t >> 6, lane = t & 63, l15 = lane & 15, q4 = lane >> 4;

#pragma unroll
  for (int i = 0; i < 16; ++i) {
    int p = i * 128 + t;
    int d = p & 63, tok8 = p >> 6;
    u16x8 v;
#pragma unroll
    for (int j = 0; j < 8; ++j) v[j] = Vb[(size_t)(tok8 * 8 + j) * D_MODEL + d];
    *(u16x8*)(vt + d * 264 + tok8 * 8) = v;
  }
  __syncthreads();

  u16* pw = pl + wave * 16 * 264;

  for (int pass = 0; pass < 8; ++pass) {
    const int r0 = pass * 32 + wave * 16;
    const int a = r0 >> 4;

    s16x8 aq[2];
#pragma unroll
    for (int kk = 0; kk < 2; ++kk)
      aq[kk] = *(const s16x8*)(Qb + (size_t)(r0 + l15) * D_MODEL + kk * 32 + q4 * 8);

    f32x4 sc[16];
#pragma unroll
    for (int i = 0; i < 16; ++i) sc[i] = {0.f, 0.f, 0.f, 0.f};

#pragma unroll
    for (int nt = 0; nt < 16; ++nt) {
      if (nt > a) break;
#pragma unroll
      for (int kk = 0; kk < 2; ++kk) {
        s16x8 bk = *(const s16x8*)(Kb + (size_t)(nt * 16 + l15) * D_MODEL + kk * 32 + q4 * 8);
        sc[nt] = __builtin_amdgcn_mfma_f32_16x16x32_bf16(aq[kk], bk, sc[nt], 0, 0, 0);
      }
    }

    float mrow[4] = {-3e38f, -3e38f, -3e38f, -3e38f};
#pragma unroll
    for (int nt = 0; nt < 16; ++nt) {
      if (nt > a) break;
#pragma unroll
      for (int r = 0; r < 4; ++r) {
        int col = nt * 16 + l15;
        int row = r0 + q4 * 4 + r;
        float s = (col > row) ? -1.0e9f : sc[nt][r] * 0.125f;
        sc[nt][r] = s;
        mrow[r] = fmaxf(mrow[r], s);
      }
    }
#pragma unroll
    for (int r = 0; r < 4; ++r)
#pragma unroll
      for (int off = 1; off < 16; off <<= 1)
        mrow[r] = fmaxf(mrow[r], __shfl_xor(mrow[r], off, 64));

    float lrow[4] = {0.f, 0.f, 0.f, 0.f};
#pragma unroll
    for (int nt = 0; nt < 16; ++nt) {
      if (nt > a) break;
#pragma unroll
      for (int r = 0; r < 4; ++r) {
        float e = exp2f((sc[nt][r] - mrow[r]) * 1.44269504f);
        sc[nt][r] = e;
        lrow[r] += e;
      }
    }
#pragma unroll
    for (int r = 0; r < 4; ++r)
#pragma unroll
      for (int off = 1; off < 16; off <<= 1)
        lrow[r] += __shfl_xor(lrow[r], off, 64);

#pragma unroll
    for (int nt = 0; nt < 16; ++nt) {
      if (nt > a) break;
#pragma unroll
      for (int r = 0; r < 4; ++r)
        pw[(q4 * 4 + r) * 264 + nt * 16 + l15] = f2bf(sc[nt][r]);
    }
    if ((a & 1) == 0) {
#pragma unroll
      for (int r = 0; r < 4; ++r)
        pw[(q4 * 4 + r) * 264 + (a + 1) * 16 + l15] = 0;
    }
    const int ktmax = (a + 2) >> 1;

    f32x4 oc[4];
#pragma unroll
    for (int i = 0; i < 4; ++i) oc[i] = {0.f, 0.f, 0.f, 0.f};
#pragma unroll
    for (int kt = 0; kt < 8; ++kt) {
      if (kt >= ktmax) break;
      s16x8 ap = *(const s16x8*)(pw + l15 * 264 + kt * 32 + q4 * 8);
#pragma unroll
      for (int dt = 0; dt < 4; ++dt) {
        s16x8 bv = *(const s16x8*)(vt + (dt * 16 + l15) * 264 + kt * 32 + q4 * 8);
        oc[dt] = __builtin_amdgcn_mfma_f32_16x16x32_bf16(ap, bv, oc[dt], 0, 0, 0);
      }
    }

    float inv[4];
#pragma unroll
    for (int r = 0; r < 4; ++r) inv[r] = 1.0f / lrow[r];
#pragma unroll
    for (int dt = 0; dt < 4; ++dt)
#pragma unroll
      for (int r = 0; r < 4; ++r)
        Ob[(size_t)(r0 + q4 * 4 + r) * D_MODEL + dt * 16 + l15] = f2bf(oc[dt][r] * inv[r]);
  }
}

extern "C" void kernel_launch(void* const* d_in, const int* in_sizes, int n_in,
                              void* d_out, int out_size, void* d_ws, size_t ws_size,
                              hipStream_t stream) {
  const float* x  = (const float*)d_in[0];
  const float* Wq = (const float*)d_in[1];
  const float* bq = (const float*)d_in[2];
  const float* Wk = (const float*)d_in[3];
  const float* bk = (const float*)d_in[4];
  const float* Wv = (const float*)d_in[5];
  const float* bv = (const float*)d_in[6];
  const float* Wo = (const float*)d_in[7];
  const float* bo = (const float*)d_in[8];
  float* out = (float*)d_out;

  // ws (bf16 internal): Wt 4x1M, xb 16M, Q/K/V 16M each. O aliases Q. Total 136 MB.
  u16* ws = (u16*)d_ws;
  u16* Wt = ws;
  u16* Xb = ws + (size_t)4 * 1048576;
  u16* Qw = Xb + (size_t)16777216;
  u16* Kw = Qw + (size_t)16777216;
  u16* Vw = Kw + (size_t)16777216;
  u16* Ow = Qw;   // alias

  cast_x<<<dim3(8192), 256, 0, stream>>>(x, Xb);
  transpose_w<<<dim3(16, 16, 4), 256, 0, stream>>>(Wq, Wk, Wv, Wo, Wt);
  gemm_qkv<<<dim3(8, 128, 3), 256, 0, stream>>>(Xb, Wt, bq, bk, bv, Qw, Kw, Vw);
  attn<<<dim3(64 * 16), 128, 0, stream>>>(Qw, Kw, Vw, Ow);
  gemm_oproj<<<dim3(8, 128, 1), 256, 0, stream>>>(Ow, Wt + (size_t)3 * 1048576, bo, out);
}

// Round 5
// 448.866 us; speedup vs baseline: 1.3976x; 1.2670x over previous
//
#include <hip/hip_runtime.h>
#include <cstdint>
#include <cstddef>

typedef unsigned short u16;
typedef __attribute__((ext_vector_type(8))) short s16x8;      // 8 bf16 = 4 VGPRs (MFMA A/B frag)
typedef __attribute__((ext_vector_type(8))) unsigned short u16x8;
typedef __attribute__((ext_vector_type(4))) float f32x4;      // MFMA C/D frag / float4 load

#define D_MODEL 1024
#define DH 64
#define BS 256
// B*S = 16384 tokens, 64 blocks of 256, 16 heads. External tensors are FLOAT32; internal bf16.

__device__ __forceinline__ u16 f2bf(float f) {
  union { float f; unsigned int i; } x; x.f = f;
  unsigned int r = x.i + 0x7fffu + ((x.i >> 16) & 1u);   // RNE
  return (u16)(r >> 16);
}

__device__ __forceinline__ void gl_lds16(const u16* g, u16* l) {
  __builtin_amdgcn_global_load_lds((const __attribute__((address_space(1))) void*)g,
                                   (__attribute__((address_space(3))) void*)l, 16, 0, 0);
}

// ---------------- cast x: f32 -> bf16, 16.7M elems ----------------
__global__ __launch_bounds__(256) void cast_x(const float* __restrict__ x, u16* __restrict__ xb) {
  int i = (blockIdx.x * 256 + threadIdx.x) * 8;
  f32x4 a0 = *(const f32x4*)(x + i);
  f32x4 a1 = *(const f32x4*)(x + i + 4);
  u16x8 v;
#pragma unroll
  for (int j = 0; j < 4; ++j) { v[j] = f2bf(a0[j]); v[j + 4] = f2bf(a1[j]); }
  *(u16x8*)(xb + i) = v;
}

// ---------------- W transpose+cast: Wt[n][k] = bf16(W[k][n]) (1024x1024 f32 -> bf16, x4) ----------------
__global__ __launch_bounds__(256) void transpose_w(const float* __restrict__ w0,
                                                   const float* __restrict__ w1,
                                                   const float* __restrict__ w2,
                                                   const float* __restrict__ w3,
                                                   u16* __restrict__ out) {
  __shared__ u16 tile[64][65];
  const int z = blockIdx.z;
  const float* W = (z == 0) ? w0 : (z == 1) ? w1 : (z == 2) ? w2 : w3;
  u16* O = out + (size_t)z * (D_MODEL * D_MODEL);
  const int kb = blockIdx.y * 64, nb = blockIdx.x * 64;
  const int t = threadIdx.x;
#pragma unroll
  for (int i = 0; i < 16; ++i) {
    int e = i * 256 + t;
    int r = e >> 6, c = e & 63;
    tile[r][c] = f2bf(W[(size_t)(kb + r) * D_MODEL + nb + c]);
  }
  __syncthreads();
#pragma unroll
  for (int i = 0; i < 16; ++i) {
    int e = i * 256 + t;
    int r = e >> 6, c = e & 63;
    O[(size_t)(nb + r) * D_MODEL + kb + c] = tile[c][r];
  }
}

// ---------------- QKV GEMM (m97 structure, z-fused): Out_z = bf16( xb @ W_z + b_z ) ----------------
// Wt is one contiguous [3072][1024] bf16 matrix (Q,K,V planes). grid (24,128):
// colGlobal = bx*128 in [0,3072); z = colGlobal>>10. Xb row-slice stays L2-hot across 24 col-tiles.
__global__ __launch_bounds__(256) void gemm_qkv(
    const u16* __restrict__ A, const u16* __restrict__ Wt,
    const float* __restrict__ bias0, const float* __restrict__ bias1, const float* __restrict__ bias2,
    u16* __restrict__ out0, u16* __restrict__ out1, u16* __restrict__ out2) {
  __shared__ u16 As[128 * 64];
  __shared__ u16 Bs[128 * 64];
  const int colG = blockIdx.x * 128;          // 0..2944
  const int z = colG >> 10;
  const float* bias = (z == 0) ? bias0 : ((z == 1) ? bias1 : bias2);
  u16* Out = (z == 0) ? out0 : ((z == 1) ? out1 : out2);
  const int rowBase = blockIdx.y * 128;
  const int t = threadIdx.x;
  const int wave = t >> 6, lane = t & 63, l15 = lane & 15, q4 = lane >> 4;
  const int wr = (wave >> 1) * 64, wc = (wave & 1) * 64;

  f32x4 acc[4][4];
#pragma unroll
  for (int i = 0; i < 4; ++i)
#pragma unroll
    for (int j = 0; j < 4; ++j) acc[i][j] = {0.f, 0.f, 0.f, 0.f};

  for (int k0 = 0; k0 < D_MODEL; k0 += 64) {
#pragma unroll
    for (int i = 0; i < 4; ++i) {
      int e = i * 256 + t;
      gl_lds16(A + (size_t)(rowBase + (e >> 3)) * D_MODEL + k0 + (e & 7) * 8, As + e * 8);
    }
#pragma unroll
    for (int i = 0; i < 4; ++i) {
      int e = i * 256 + t;
      gl_lds16(Wt + (size_t)(colG + (e >> 3)) * D_MODEL + k0 + (e & 7) * 8, Bs + e * 8);
    }
    __syncthreads();
#pragma unroll
    for (int kk = 0; kk < 2; ++kk) {
      s16x8 af[4], bf[4];
#pragma unroll
      for (int mt = 0; mt < 4; ++mt)
        af[mt] = *(const s16x8*)(As + (wr + mt * 16 + l15) * 64 + kk * 32 + q4 * 8);
#pragma unroll
      for (int nt = 0; nt < 4; ++nt)
        bf[nt] = *(const s16x8*)(Bs + (wc + nt * 16 + l15) * 64 + kk * 32 + q4 * 8);
#pragma unroll
      for (int mt = 0; mt < 4; ++mt)
#pragma unroll
        for (int nt = 0; nt < 4; ++nt)
          acc[mt][nt] = __builtin_amdgcn_mfma_f32_16x16x32_bf16(af[mt], bf[nt], acc[mt][nt], 0, 0, 0);
    }
    __syncthreads();
  }

#pragma unroll
  for (int nt = 0; nt < 4; ++nt) {
    int col = (colG & 1023) + wc + nt * 16 + l15;
    float bv = bias[col];
#pragma unroll
    for (int mt = 0; mt < 4; ++mt) {
      int row0 = rowBase + wr + mt * 16 + q4 * 4;
#pragma unroll
      for (int r = 0; r < 4; ++r)
        Out[(size_t)(row0 + r) * D_MODEL + col] = f2bf(acc[mt][nt][r] + bv);
    }
  }
}

// ---------------- O-proj GEMM (m97 structure): out = f32( Ow @ Wo + bo ) ----------------
__global__ __launch_bounds__(256) void gemm_oproj(
    const u16* __restrict__ A, const u16* __restrict__ Wt,
    const float* __restrict__ bias, float* __restrict__ Out) {
  __shared__ u16 As[128 * 64];
  __shared__ u16 Bs[128 * 64];
  const int rowBase = blockIdx.y * 128;
  const int colBase = blockIdx.x * 128;
  const int t = threadIdx.x;
  const int wave = t >> 6, lane = t & 63, l15 = lane & 15, q4 = lane >> 4;
  const int wr = (wave >> 1) * 64, wc = (wave & 1) * 64;

  f32x4 acc[4][4];
#pragma unroll
  for (int i = 0; i < 4; ++i)
#pragma unroll
    for (int j = 0; j < 4; ++j) acc[i][j] = {0.f, 0.f, 0.f, 0.f};

  for (int k0 = 0; k0 < D_MODEL; k0 += 64) {
#pragma unroll
    for (int i = 0; i < 4; ++i) {
      int e = i * 256 + t;
      gl_lds16(A + (size_t)(rowBase + (e >> 3)) * D_MODEL + k0 + (e & 7) * 8, As + e * 8);
    }
#pragma unroll
    for (int i = 0; i < 4; ++i) {
      int e = i * 256 + t;
      gl_lds16(Wt + (size_t)(colBase + (e >> 3)) * D_MODEL + k0 + (e & 7) * 8, Bs + e * 8);
    }
    __syncthreads();
#pragma unroll
    for (int kk = 0; kk < 2; ++kk) {
      s16x8 af[4], bf[4];
#pragma unroll
      for (int mt = 0; mt < 4; ++mt)
        af[mt] = *(const s16x8*)(As + (wr + mt * 16 + l15) * 64 + kk * 32 + q4 * 8);
#pragma unroll
      for (int nt = 0; nt < 4; ++nt)
        bf[nt] = *(const s16x8*)(Bs + (wc + nt * 16 + l15) * 64 + kk * 32 + q4 * 8);
#pragma unroll
      for (int mt = 0; mt < 4; ++mt)
#pragma unroll
        for (int nt = 0; nt < 4; ++nt)
          acc[mt][nt] = __builtin_amdgcn_mfma_f32_16x16x32_bf16(af[mt], bf[nt], acc[mt][nt], 0, 0, 0);
    }
    __syncthreads();
  }

#pragma unroll
  for (int nt = 0; nt < 4; ++nt) {
    int col = colBase + wc + nt * 16 + l15;
    float bv = bias[col];
#pragma unroll
    for (int mt = 0; mt < 4; ++mt) {
      int row0 = rowBase + wr + mt * 16 + q4 * 4;
#pragma unroll
      for (int r = 0; r < 4; ++r)
        Out[(size_t)(row0 + r) * D_MODEL + col] = acc[mt][nt][r] + bv;
    }
  }
}

// ---------------- Attention: one WG (128 thr = 2 waves) per (block n, head h) ----------------
// All causal-skip conditions are wave-uniform guards inside constant-trip unrolled loops
// (NO dynamic break: a break defeats unrolling and forces sc[] into scratch — R4 lesson).
__global__ __launch_bounds__(128) void attn(const u16* __restrict__ Q, const u16* __restrict__ K,
                                            const u16* __restrict__ V, u16* __restrict__ O) {
  __shared__ u16 vt[64 * 264];        // V^T: [d][tok], row stride 264
  __shared__ u16 pl[2 * 16 * 264];    // per-wave P / O staging: [wave][16 rows][256(+pad) cols]
  const int g = blockIdx.x;
  const int n = g >> 4, h = g & 15;
  const size_t base = (size_t)n * BS * D_MODEL + (size_t)h * DH;
  const u16* Qb = Q + base;
  const u16* Kb = K + base;
  const u16* Vb = V + base;
  u16* Ob = O + base;
  const int t = threadIdx.x, wave = t >> 6, lane = t & 63, l15 = lane & 15, q4 = lane >> 4;

#pragma unroll
  for (int i = 0; i < 16; ++i) {
    int p = i * 128 + t;
    int d = p & 63, tok8 = p >> 6;
    u16x8 v;
#pragma unroll
    for (int j = 0; j < 8; ++j) v[j] = Vb[(size_t)(tok8 * 8 + j) * D_MODEL + d];
    *(u16x8*)(vt + d * 264 + tok8 * 8) = v;
  }
  __syncthreads();

  u16* pw = pl + wave * 16 * 264;

  for (int pass = 0; pass < 8; ++pass) {
    const int r0 = pass * 32 + wave * 16;
    const int a = r0 >> 4;              // = 2*pass + wave, wave-uniform

    s16x8 aq[2];
#pragma unroll
    for (int kk = 0; kk < 2; ++kk)
      aq[kk] = *(const s16x8*)(Qb + (size_t)(r0 + l15) * D_MODEL + kk * 32 + q4 * 8);

    f32x4 sc[16];
#pragma unroll
    for (int i = 0; i < 16; ++i) sc[i] = {0.f, 0.f, 0.f, 0.f};

#pragma unroll
    for (int nt = 0; nt < 16; ++nt) {
      if (nt <= a) {
#pragma unroll
        for (int kk = 0; kk < 2; ++kk) {
          s16x8 bk = *(const s16x8*)(Kb + (size_t)(nt * 16 + l15) * D_MODEL + kk * 32 + q4 * 8);
          sc[nt] = __builtin_amdgcn_mfma_f32_16x16x32_bf16(aq[kk], bk, sc[nt], 0, 0, 0);
        }
      }
    }

    float mrow[4] = {-3e38f, -3e38f, -3e38f, -3e38f};
#pragma unroll
    for (int nt = 0; nt < 16; ++nt) {
      if (nt <= a) {
#pragma unroll
        for (int r = 0; r < 4; ++r) {
          int col = nt * 16 + l15;
          int row = r0 + q4 * 4 + r;
          float s = (col > row) ? -1.0e9f : sc[nt][r] * 0.125f;
          sc[nt][r] = s;
          mrow[r] = fmaxf(mrow[r], s);
        }
      }
    }
#pragma unroll
    for (int r = 0; r < 4; ++r)
#pragma unroll
      for (int off = 1; off < 16; off <<= 1)
        mrow[r] = fmaxf(mrow[r], __shfl_xor(mrow[r], off, 64));

    float lrow[4] = {0.f, 0.f, 0.f, 0.f};
#pragma unroll
    for (int nt = 0; nt < 16; ++nt) {
      if (nt <= a) {
#pragma unroll
        for (int r = 0; r < 4; ++r) {
          float e = exp2f((sc[nt][r] - mrow[r]) * 1.44269504f);
          sc[nt][r] = e;
          lrow[r] += e;
        }
      }
    }
#pragma unroll
    for (int r = 0; r < 4; ++r)
#pragma unroll
      for (int off = 1; off < 16; off <<= 1)
        lrow[r] += __shfl_xor(lrow[r], off, 64);

#pragma unroll
    for (int nt = 0; nt < 16; ++nt) {
      if (nt <= a) {
#pragma unroll
        for (int r = 0; r < 4; ++r)
          pw[(q4 * 4 + r) * 264 + nt * 16 + l15] = f2bf(sc[nt][r]);
      }
    }
    if ((a & 1) == 0) {                 // zero partner tile for the K=32 PV step
#pragma unroll
      for (int r = 0; r < 4; ++r)
        pw[(q4 * 4 + r) * 264 + (a + 1) * 16 + l15] = 0;
    }
    const int ktmax = (a + 2) >> 1;

    f32x4 oc[4];
#pragma unroll
    for (int i = 0; i < 4; ++i) oc[i] = {0.f, 0.f, 0.f, 0.f};
#pragma unroll
    for (int kt = 0; kt < 8; ++kt) {
      if (kt < ktmax) {
        s16x8 ap = *(const s16x8*)(pw + l15 * 264 + kt * 32 + q4 * 8);
#pragma unroll
        for (int dt = 0; dt < 4; ++dt) {
          s16x8 bv = *(const s16x8*)(vt + (dt * 16 + l15) * 264 + kt * 32 + q4 * 8);
          oc[dt] = __builtin_amdgcn_mfma_f32_16x16x32_bf16(ap, bv, oc[dt], 0, 0, 0);
        }
      }
    }

    float inv[4];
#pragma unroll
    for (int r = 0; r < 4; ++r) inv[r] = 1.0f / lrow[r];

    // normalize, stage O tile (16 rows x 64 cols) in per-wave LDS, then b128 coalesced stores
#pragma unroll
    for (int dt = 0; dt < 4; ++dt)
#pragma unroll
      for (int r = 0; r < 4; ++r)
        pw[(q4 * 4 + r) * 264 + dt * 16 + l15] = f2bf(oc[dt][r] * inv[r]);
#pragma unroll
    for (int k = 0; k < 2; ++k) {
      int c2 = k * 64 + lane;
      int row = c2 >> 3, c8 = (c2 & 7) * 8;
      u16x8 v = *(const u16x8*)(pw + row * 264 + c8);
      *(u16x8*)(Ob + (size_t)(r0 + row) * D_MODEL + c8) = v;
    }
  }
}

extern "C" void kernel_launch(void* const* d_in, const int* in_sizes, int n_in,
                              void* d_out, int out_size, void* d_ws, size_t ws_size,
                              hipStream_t stream) {
  const float* x  = (const float*)d_in[0];
  const float* Wq = (const float*)d_in[1];
  const float* bq = (const float*)d_in[2];
  const float* Wk = (const float*)d_in[3];
  const float* bk = (const float*)d_in[4];
  const float* Wv = (const float*)d_in[5];
  const float* bv = (const float*)d_in[6];
  const float* Wo = (const float*)d_in[7];
  const float* bo = (const float*)d_in[8];
  float* out = (float*)d_out;

  // ws (bf16 internal): Wt 4x1M, xb 16M, Q/K/V 16M each. O aliases Q. Total 136 MB.
  u16* ws = (u16*)d_ws;
  u16* Wt = ws;
  u16* Xb = ws + (size_t)4 * 1048576;
  u16* Qw = Xb + (size_t)16777216;
  u16* Kw = Qw + (size_t)16777216;
  u16* Vw = Kw + (size_t)16777216;
  u16* Ow = Qw;   // alias

  cast_x<<<dim3(8192), 256, 0, stream>>>(x, Xb);
  transpose_w<<<dim3(16, 16, 4), 256, 0, stream>>>(Wq, Wk, Wv, Wo, Wt);
  gemm_qkv<<<dim3(24, 128), 256, 0, stream>>>(Xb, Wt, bq, bk, bv, Qw, Kw, Vw);
  attn<<<dim3(64 * 16), 128, 0, stream>>>(Qw, Kw, Vw, Ow);
  gemm_oproj<<<dim3(8, 128, 1), 256, 0, stream>>>(Ow, Wt + (size_t)3 * 1048576, bo, out);
}